// Round 10
// baseline (133.104 us; speedup 1.0000x reference)
//
#include <hip/hip_runtime.h>
#include <hip/hip_bf16.h>

// GPT2 attention. B=2, S=2048, D=1024, H=16, DH=64.
// inputs (f32): x[2,2048,1024], w_attn[1024,3072], b_attn[3072], w_proj[1024,1024], b_proj[1024]
// output (f32): [2,2048,1024]

#define BB 2
#define SS 2048
#define DD 1024
#define HH 16
#define DHH 64
#define MTOK (BB * SS)        // 4096
#define N3D (3 * DD)          // 3072

typedef __attribute__((ext_vector_type(8))) short bf16x8;
typedef __attribute__((ext_vector_type(4))) float f32x4;
typedef __attribute__((ext_vector_type(4))) short short4v;

__device__ __forceinline__ short f2bf(float f) {
  unsigned int x = __float_as_uint(f);
  unsigned int r = (x + 0x7fffu + ((x >> 16) & 1u)) >> 16;
  return (short)r;
}

__device__ __forceinline__ unsigned int cvtpk_bf16(float lo, float hi) {
  unsigned int r;
  asm("v_cvt_pk_bf16_f32 %0, %1, %2" : "=v"(r) : "v"(lo), "v"(hi));
  return r;
}

// ---------------- cast f32 -> bf16 (vectorized x4) ----------------
__global__ void cast_bf16_k(const float* __restrict__ in, short* __restrict__ out, int n4) {
  int i = blockIdx.x * blockDim.x + threadIdx.x;
  if (i < n4) {
    float4 v = reinterpret_cast<const float4*>(in)[i];
    short4v o;
    o[0] = f2bf(v.x); o[1] = f2bf(v.y); o[2] = f2bf(v.z); o[3] = f2bf(v.w);
    reinterpret_cast<short4v*>(out)[i] = o;
  }
}

// ---------------- transpose + cast: W[K][N] f32 -> Wt[N][K] bf16 ----------------
__global__ void transpose_cast_k(const float* __restrict__ W, short* __restrict__ Wt, int K, int N) {
  __shared__ float t[32][33];
  int n0 = blockIdx.x * 32, k0 = blockIdx.y * 32;
  int tx = threadIdx.x, ty = threadIdx.y;
#pragma unroll
  for (int i = 0; i < 4; ++i)
    t[ty + 8 * i][tx] = W[(size_t)(k0 + ty + 8 * i) * N + n0 + tx];
  __syncthreads();
#pragma unroll
  for (int i = 0; i < 4; ++i)
    Wt[(size_t)(n0 + ty + 8 * i) * K + k0 + tx] = f2bf(t[tx][ty + 8 * i]);
}

// ---------------- extract V^T per (b,h): Vt[(b*H+h)*64+d][s] ----------------
__global__ void extract_vt_k(const short* __restrict__ qkv, short* __restrict__ vt) {
  __shared__ short t[32][33];
  int s0 = blockIdx.x * 32, d0 = blockIdx.y * 32;
  int bh = blockIdx.z;
  int b = bh >> 4, h = bh & 15;
  int tx = threadIdx.x, ty = threadIdx.y;
#pragma unroll
  for (int i = 0; i < 4; ++i)
    t[ty + 8 * i][tx] =
        qkv[(size_t)(b * SS + s0 + ty + 8 * i) * N3D + 2 * DD + h * DHH + d0 + tx];
  __syncthreads();
#pragma unroll
  for (int i = 0; i < 4; ++i)
    vt[(size_t)(bh * DHH + d0 + ty + 8 * i) * SS + s0 + tx] = t[tx][ty + 8 * i];
}

// ---------------- GEMM m97-structure: C[M][N] = A[M][K] * Bt[N][K]^T + bias ----------------
// OUTF32=0: bf16 out, pre-scales Q columns (col < DD) by 0.125, LDS-bounce coalesced
// epilogue (25MB of scalar-short stores was ~15-20us of the QKV dispatch).
// OUTF32=1: f32 out, direct dword stores (unchanged).
template <int OUTF32>
__global__ __launch_bounds__(256) void gemm128_k(const short* __restrict__ A,
                                                 const short* __restrict__ Bt,
                                                 const float* __restrict__ bias,
                                                 void* __restrict__ Cout,
                                                 int M, int N, int K) {
  // [0,16384) As ; [16384,32768) Bs ; epilogue bf16 tile aliases [0,33792): 128 rows x 132 shorts
  __shared__ __align__(16) char smem_g[33792];
  short* As = reinterpret_cast<short*>(smem_g);
  short* Bs = reinterpret_cast<short*>(smem_g + 16384);
  short* Ep = reinterpret_cast<short*>(smem_g);
  int tid = threadIdx.x;
  int m0 = blockIdx.y * 128, n0 = blockIdx.x * 128;
  int w = tid >> 6, lane = tid & 63;
  int wr = w >> 1, wc = w & 1;
  int ln16 = lane & 15, l16 = lane >> 4;

  f32x4 acc[4][4] = {};

  int lrow0 = w * 32 + (lane >> 3);
  int blk_p = lane & 7;

  for (int k0 = 0; k0 < K; k0 += 64) {
#pragma unroll
    for (int i = 0; i < 4; ++i) {
      int row_p = lrow0 + i * 8;
      int colE = ((blk_p ^ (row_p & 7)) << 3);
      __builtin_amdgcn_global_load_lds(
          (const __attribute__((address_space(1))) unsigned int*)&A[(size_t)(m0 + row_p) * K + k0 + colE],
          (__attribute__((address_space(3))) unsigned int*)&As[(w * 4 + i) * 512],
          16, 0, 0);
      __builtin_amdgcn_global_load_lds(
          (const __attribute__((address_space(1))) unsigned int*)&Bt[(size_t)(n0 + row_p) * K + k0 + colE],
          (__attribute__((address_space(3))) unsigned int*)&Bs[(w * 4 + i) * 512],
          16, 0, 0);
    }
    __syncthreads();
#pragma unroll
    for (int kk = 0; kk < 2; ++kk) {
      bf16x8 a[4], bfr[4];
#pragma unroll
      for (int mi = 0; mi < 4; ++mi) {
        int row = wr * 64 + mi * 16 + ln16;
        int blk = (kk * 4 + l16) ^ (row & 7);
        a[mi] = *reinterpret_cast<const bf16x8*>(&As[row * 64 + blk * 8]);
      }
#pragma unroll
      for (int ni = 0; ni < 4; ++ni) {
        int row = wc * 64 + ni * 16 + ln16;
        int blk = (kk * 4 + l16) ^ (row & 7);
        bfr[ni] = *reinterpret_cast<const bf16x8*>(&Bs[row * 64 + blk * 8]);
      }
#pragma unroll
      for (int mi = 0; mi < 4; ++mi)
#pragma unroll
        for (int ni = 0; ni < 4; ++ni)
          acc[mi][ni] = __builtin_amdgcn_mfma_f32_16x16x32_bf16(a[mi], bfr[ni], acc[mi][ni], 0, 0, 0);
    }
    __syncthreads();
  }

  if (OUTF32) {
#pragma unroll
    for (int mi = 0; mi < 4; ++mi)
#pragma unroll
      for (int ni = 0; ni < 4; ++ni)
#pragma unroll
        for (int ri = 0; ri < 4; ++ri) {
          int row = m0 + wr * 64 + mi * 16 + l16 * 4 + ri;
          int col = n0 + wc * 64 + ni * 16 + ln16;
          reinterpret_cast<float*>(Cout)[(size_t)row * N + col] = acc[mi][ni][ri] + bias[col];
        }
  } else {
    // bias + scale + bf16 into padded LDS tile (row stride 132 shorts; writes spread 32 banks)
#pragma unroll
    for (int mi = 0; mi < 4; ++mi)
#pragma unroll
      for (int ni = 0; ni < 4; ++ni)
#pragma unroll
        for (int ri = 0; ri < 4; ++ri) {
          int lrow = wr * 64 + mi * 16 + l16 * 4 + ri;
          int lcol = wc * 64 + ni * 16 + ln16;
          float v = acc[mi][ni][ri] + bias[n0 + lcol];
          if (n0 + lcol < DD) v *= 0.125f;  // pre-scale Q by 1/sqrt(DH)
          Ep[lrow * 132 + lcol] = f2bf(v);
        }
    __syncthreads();
    // coalesced store: thread t -> row t>>1, half t&1 (64 consecutive shorts = 128B)
    int r = tid >> 1, hf = tid & 1;
    const short* src = Ep + r * 132 + hf * 64;
    short* dst = reinterpret_cast<short*>(Cout) + (size_t)(m0 + r) * N + n0 + hf * 64;
    uint2 tmp[16];
#pragma unroll
    for (int i = 0; i < 16; ++i) tmp[i] = reinterpret_cast<const uint2*>(src)[i];
#pragma unroll
    for (int i = 0; i < 8; ++i) {
      uint4 u;
      u.x = tmp[2 * i].x; u.y = tmp[2 * i].y;
      u.z = tmp[2 * i + 1].x; u.w = tmp[2 * i + 1].y;
      reinterpret_cast<uint4*>(dst)[i] = u;
    }
  }
}

// ---------------- Flash attention (round-5 proven): 8 waves, even/odd KV split, paired q-tiles ----------------
// grid (16, B*H), 512 threads. Waves 0-3 (g=0): even kt; waves 4-7 (g=1): odd kt.
// Wave wq owns q-rows [wq*16, wq*16+16). Block does q-tiles 31-pj then pj (uniform work).
// LDS = 53248 B.
#define MASKV -3.0e38f
__global__ __launch_bounds__(512) void flash_attn_k(const short* __restrict__ qkv,
                                                    const short* __restrict__ vt,
                                                    short* __restrict__ ctx) {
  __shared__ __align__(16) char smem[53248];
  // [0,18432): Ks[2][64][72] ; [18432,36864): Vs[2][64][72] ; [36864,53248): Ps 8*16*64 shorts
  // (XOR-swizzled 16B blocks). Combine aliases: Od f32 dump at [0,16640), mls at [17408,17920).
  short (*Ks)[64][72] = reinterpret_cast<short(*)[64][72]>(smem);
  short (*Vs)[64][72] = reinterpret_cast<short(*)[64][72]>(smem + 18432);
  short* Psr = reinterpret_cast<short*>(smem + 36864);
  float* Od = reinterpret_cast<float*>(smem);
  float* mls = reinterpret_cast<float*>(smem + 17408);

  int tid = threadIdx.x;
  int pj = blockIdx.x;
  int bh = blockIdx.y;
  int b = bh >> 4, h = bh & 15;
  int wg = tid >> 6, lane = tid & 63;
  int g = wg >> 2, wq = wg & 3;
  int ln16 = lane & 15, l16 = lane >> 4;
  int t8 = tid & 255;
  int tb = tid >> 8;  // staging parity buffer this thread fills
  int r0 = t8 >> 3, cc0 = (t8 & 7) << 3;
  int psq = (wg << 10) + (ln16 << 6);  // Ps base (shorts) for this wave+q

  const short* kbase = qkv + (size_t)(b * SS) * N3D + DD + h * DHH;  // + s*N3D + d
  const short* vbase = vt + (size_t)(bh * DHH) * SS;                 // + d*SS + s

#pragma unroll 1
  for (int ti = 0; ti < 2; ++ti) {
    int qt = ti ? pj : 31 - pj;
    int q0 = qt * 64;

    bf16x8 qf[2];
    {
      const short* qrow = qkv + (size_t)(b * SS + q0 + wq * 16 + ln16) * N3D + h * DHH;
      qf[0] = *reinterpret_cast<const bf16x8*>(qrow + l16 * 8);
      qf[1] = *reinterpret_cast<const bf16x8*>(qrow + 32 + l16 * 8);
    }
    float m_ = -1e30f, l_ = 0.f;
    f32x4 cacc[4] = {};

    int ns = (qt + 2) >> 1;
    uint4 kr0, kr1, vr0, vr1;
    {
      int kt_s = tb <= qt ? tb : qt;
      kr0 = *reinterpret_cast<const uint4*>(kbase + (size_t)(kt_s * 64 + r0) * N3D + cc0);
      kr1 = *reinterpret_cast<const uint4*>(kbase + (size_t)(kt_s * 64 + r0 + 32) * N3D + cc0);
      vr0 = *reinterpret_cast<const uint4*>(vbase + (size_t)r0 * SS + kt_s * 64 + cc0);
      vr1 = *reinterpret_cast<const uint4*>(vbase + (size_t)(r0 + 32) * SS + kt_s * 64 + cc0);
    }

#pragma unroll 1
    for (int s = 0; s < ns; ++s) {
      *reinterpret_cast<uint4*>(&Ks[tb][r0][cc0]) = kr0;
      *reinterpret_cast<uint4*>(&Ks[tb][r0 + 32][cc0]) = kr1;
      *reinterpret_cast<uint4*>(&Vs[tb][r0][cc0]) = vr0;
      *reinterpret_cast<uint4*>(&Vs[tb][r0 + 32][cc0]) = vr1;
      __syncthreads();

      // prefetch next super-iter (clamped; latency hides under softmax+PV)
      {
        int kt_n = 2 * (s + 1) + tb;
        if (kt_n > qt) kt_n = qt;
        kr0 = *reinterpret_cast<const uint4*>(kbase + (size_t)(kt_n * 64 + r0) * N3D + cc0);
        kr1 = *reinterpret_cast<const uint4*>(kbase + (size_t)(kt_n * 64 + r0 + 32) * N3D + cc0);
        vr0 = *reinterpret_cast<const uint4*>(vbase + (size_t)r0 * SS + kt_n * 64 + cc0);
        vr1 = *reinterpret_cast<const uint4*>(vbase + (size_t)(r0 + 32) * SS + kt_n * 64 + cc0);
      }

      int kt_c = 2 * s + g;
      if (kt_c <= qt) {
        // QK^T swapped: sacc[ni][ri] = S^T[k = ni*16+l16*4+ri][q = ln16]  (Q pre-scaled)
        f32x4 sacc[4] = {};
#pragma unroll
        for (int kk = 0; kk < 2; ++kk)
#pragma unroll
          for (int ni = 0; ni < 4; ++ni) {
            bf16x8 kf = *reinterpret_cast<const bf16x8*>(&Ks[g][ni * 16 + ln16][kk * 32 + l16 * 8]);
            sacc[ni] = __builtin_amdgcn_mfma_f32_16x16x32_bf16(kf, qf[kk], sacc[ni], 0, 0, 0);
          }

        float p[4][4];
        float mx = MASKV;
        if (kt_c == qt) {  // diagonal tile: causal mask
          int qg = q0 + wq * 16 + ln16;
#pragma unroll
          for (int ni = 0; ni < 4; ++ni)
#pragma unroll
            for (int ri = 0; ri < 4; ++ri) {
              int kg = kt_c * 64 + ni * 16 + l16 * 4 + ri;
              float v = (kg > qg) ? MASKV : sacc[ni][ri];
              p[ni][ri] = v;
              mx = fmaxf(mx, v);
            }
        } else {
#pragma unroll
          for (int ni = 0; ni < 4; ++ni)
#pragma unroll
            for (int ri = 0; ri < 4; ++ri) {
              p[ni][ri] = sacc[ni][ri];
              mx = fmaxf(mx, sacc[ni][ri]);
            }
        }
        mx = fmaxf(mx, __shfl_xor(mx, 16));
        mx = fmaxf(mx, __shfl_xor(mx, 32));

        // defer-max (T13): only rescale when max grew by > 8
        int keep = __all(mx <= m_ + 8.0f);
        float mn = m_;
        if (!keep) {
          mn = fmaxf(m_, mx);
          float sc = __expf(m_ - mn);
          l_ *= sc;
          float scr[4];
#pragma unroll
          for (int ri = 0; ri < 4; ++ri) scr[ri] = __shfl(sc, l16 * 4 + ri);
#pragma unroll
          for (int di = 0; di < 4; ++di)
#pragma unroll
            for (int ri = 0; ri < 4; ++ri) cacc[di][ri] *= scr[ri];
          m_ = mn;
        }

        float sum = 0.f;
#pragma unroll
        for (int ni = 0; ni < 4; ++ni)
#pragma unroll
          for (int ri = 0; ri < 4; ++ri) {
            float e = __expf(p[ni][ri] - mn);
            p[ni][ri] = e;
            sum += e;
          }
        sum += __shfl_xor(sum, 16);
        sum += __shfl_xor(sum, 32);
        l_ += sum;

        // pack P -> Ps[wave][q=ln16][k], XOR-swizzled 16B blocks (blk ^= q&7)
#pragma unroll
        for (int ni = 0; ni < 4; ++ni) {
          uint2 u;
          u.x = cvtpk_bf16(p[ni][0], p[ni][1]);
          u.y = cvtpk_bf16(p[ni][2], p[ni][3]);
          int idx = psq + ((((ni << 1) + (l16 >> 1)) ^ (ln16 & 7)) << 3) + ((l16 & 1) << 2);
          *reinterpret_cast<uint2*>(&Psr[idx]) = u;
        }
        asm volatile("s_waitcnt lgkmcnt(0)" ::: "memory");

        // ctx += P @ V
#pragma unroll
        for (int kk = 0; kk < 2; ++kk) {
          bf16x8 pa = *reinterpret_cast<const bf16x8*>(
              &Psr[psq + ((((kk << 2) + l16) ^ (ln16 & 7)) << 3)]);
#pragma unroll
          for (int di = 0; di < 4; ++di) {
            bf16x8 vb = *reinterpret_cast<const bf16x8*>(&Vs[g][di * 16 + ln16][kk * 32 + l16 * 8]);
            cacc[di] = __builtin_amdgcn_mfma_f32_16x16x32_bf16(pa, vb, cacc[di], 0, 0, 0);
          }
        }
      }
      __syncthreads();
    }

    // ---- combine even/odd partials (aliases Ks/Vs region; all kv reads done) ----
    if (g == 1) {
      if (l16 == 0) { mls[wq * 16 + ln16] = m_; mls[64 + wq * 16 + ln16] = l_; }
#pragma unroll
      for (int di = 0; di < 4; ++di)
#pragma unroll
        for (int ri = 0; ri < 4; ++ri)
          Od[wq * 1040 + (l16 * 4 + ri) * 65 + di * 16 + ln16] = cacc[di][ri];
    }
    __syncthreads();
    if (g == 0) {
      float m1 = mls[wq * 16 + ln16], l1 = mls[64 + wq * 16 + ln16];
      float mM = fmaxf(m_, m1);
      float e0 = __expf(m_ - mM), e1 = __expf(m1 - mM);
      float inv = 1.f / (l_ * e0 + l1 * e1);
      float e0r[4], e1r[4], ivr[4];
#pragma unroll
      for (int ri = 0; ri < 4; ++ri) {
        int src = l16 * 4 + ri;
        e0r[ri] = __shfl(e0, src);
        e1r[ri] = __shfl(e1, src);
        ivr[ri] = __shfl(inv, src);
      }
#pragma unroll
      for (int di = 0; di < 4; ++di)
#pragma unroll
        for (int ri = 0; ri < 4; ++ri) {
          float a1 = Od[wq * 1040 + (l16 * 4 + ri) * 65 + di * 16 + ln16];
          float o = (cacc[di][ri] * e0r[ri] + a1 * e1r[ri]) * ivr[ri];
          int row = q0 + wq * 16 + l16 * 4 + ri;
          int col = h * DHH + di * 16 + ln16;
          ctx[(size_t)(b * SS + row) * DD + col] = f2bf(o);
        }
    }
    __syncthreads();
  }
}

extern "C" void kernel_launch(void* const* d_in, const int* in_sizes, int n_in,
                              void* d_out, int out_size, void* d_ws, size_t ws_size,
                              hipStream_t stream) {
  const float* x      = (const float*)d_in[0];
  const float* w_attn = (const float*)d_in[1];
  const float* b_attn = (const float*)d_in[2];
  const float* w_proj = (const float*)d_in[3];
  const float* b_proj = (const float*)d_in[4];
  float* out = (float*)d_out;

  char* ws = (char*)d_ws;
  short* xb     = (short*)(ws);                       // 8388608 B
  short* wattnT = (short*)(ws + 8388608);             // 6291456 B
  short* wprojT = (short*)(ws + 14680064);            // 2097152 B
  short* qkv    = (short*)(ws + 16777216);            // 25165824 B
  short* vt     = (short*)(ws + 41943040);            // 8388608 B
  short* ctx    = (short*)(ws + 50331648);            // 8388608 B

  {
    int n4 = (MTOK * DD) / 4;
    cast_bf16_k<<<(n4 + 255) / 256, 256, 0, stream>>>(x, xb, n4);
  }
  transpose_cast_k<<<dim3(N3D / 32, DD / 32), dim3(32, 8), 0, stream>>>(w_attn, wattnT, DD, N3D);
  transpose_cast_k<<<dim3(DD / 32, DD / 32), dim3(32, 8), 0, stream>>>(w_proj, wprojT, DD, DD);
  gemm128_k<0><<<dim3(N3D / 128, MTOK / 128), 256, 0, stream>>>(xb, wattnT, b_attn, qkv, MTOK, N3D, DD);
  extract_vt_k<<<dim3(SS / 32, DHH / 32, BB * HH), dim3(32, 8), 0, stream>>>(qkv, vt);
  flash_attn_k<<<dim3(16, BB * HH), 512, 0, stream>>>(qkv, vt, ctx);
  gemm128_k<1><<<dim3(DD / 128, MTOK / 128), 256, 0, stream>>>(ctx, wprojT, b_proj, out, MTOK, DD, DD);
}

// Round 11
// 128.380 us; speedup vs baseline: 1.0368x; 1.0368x over previous
//
#include <hip/hip_runtime.h>
#include <hip/hip_bf16.h>

// GPT2 attention. B=2, S=2048, D=1024, H=16, DH=64.
// inputs (f32): x[2,2048,1024], w_attn[1024,3072], b_attn[3072], w_proj[1024,1024], b_proj[1024]
// output (f32): [2,2048,1024]

#define BB 2
#define SS 2048
#define DD 1024
#define HH 16
#define DHH 64
#define MTOK (BB * SS)        // 4096
#define N3D (3 * DD)          // 3072
// 1/sqrt(64) * log2(e): softmax runs in exp2 domain
#define QSCALE 0.18033688f

typedef __attribute__((ext_vector_type(8))) short bf16x8;
typedef __attribute__((ext_vector_type(4))) float f32x4;
typedef __attribute__((ext_vector_type(4))) short short4v;

__device__ __forceinline__ short f2bf(float f) {
  unsigned int x = __float_as_uint(f);
  unsigned int r = (x + 0x7fffu + ((x >> 16) & 1u)) >> 16;
  return (short)r;
}

__device__ __forceinline__ unsigned int cvtpk_bf16(float lo, float hi) {
  unsigned int r;
  asm("v_cvt_pk_bf16_f32 %0, %1, %2" : "=v"(r) : "v"(lo), "v"(hi));
  return r;
}

// ---------------- cast f32 -> bf16 (vectorized x4) ----------------
__global__ void cast_bf16_k(const float* __restrict__ in, short* __restrict__ out, int n4) {
  int i = blockIdx.x * blockDim.x + threadIdx.x;
  if (i < n4) {
    float4 v = reinterpret_cast<const float4*>(in)[i];
    short4v o;
    o[0] = f2bf(v.x); o[1] = f2bf(v.y); o[2] = f2bf(v.z); o[3] = f2bf(v.w);
    reinterpret_cast<short4v*>(out)[i] = o;
  }
}

// ---------------- transpose + cast: W[K][N] f32 -> Wt[N][K] bf16 ----------------
__global__ void transpose_cast_k(const float* __restrict__ W, short* __restrict__ Wt, int K, int N) {
  __shared__ float t[32][33];
  int n0 = blockIdx.x * 32, k0 = blockIdx.y * 32;
  int tx = threadIdx.x, ty = threadIdx.y;
#pragma unroll
  for (int i = 0; i < 4; ++i)
    t[ty + 8 * i][tx] = W[(size_t)(k0 + ty + 8 * i) * N + n0 + tx];
  __syncthreads();
#pragma unroll
  for (int i = 0; i < 4; ++i)
    Wt[(size_t)(n0 + ty + 8 * i) * K + k0 + tx] = f2bf(t[tx][ty + 8 * i]);
}

// ---------------- GEMM m97-structure: C[M][N] = A[M][K] * Bt[N][K]^T + bias ----------------
// OUTF32=0 (QKV): bf16 out; Q cols (n0<DD) pre-scaled by QSCALE; V cols (n0>=2DD) are
// written TRANSPOSED to vtout (vt[(b*1024 + col-2048)][s]) instead of qkv -- the flash
// kernel reads V only via vt, and scattered 2B stores through L2 measured cheap (R10).
// OUTF32=1 (proj): f32 out, direct dword stores.
template <int OUTF32>
__global__ __launch_bounds__(256) void gemm128_k(const short* __restrict__ A,
                                                 const short* __restrict__ Bt,
                                                 const float* __restrict__ bias,
                                                 void* __restrict__ Cout,
                                                 short* __restrict__ vtout,
                                                 int M, int N, int K) {
  __shared__ short As[128 * 64];
  __shared__ short Bs[128 * 64];
  int tid = threadIdx.x;
  int m0 = blockIdx.y * 128, n0 = blockIdx.x * 128;
  int w = tid >> 6, lane = tid & 63;
  int wr = w >> 1, wc = w & 1;
  int ln16 = lane & 15, l16 = lane >> 4;

  f32x4 acc[4][4] = {};

  int lrow0 = w * 32 + (lane >> 3);
  int blk_p = lane & 7;

  for (int k0 = 0; k0 < K; k0 += 64) {
#pragma unroll
    for (int i = 0; i < 4; ++i) {
      int row_p = lrow0 + i * 8;
      int colE = ((blk_p ^ (row_p & 7)) << 3);
      __builtin_amdgcn_global_load_lds(
          (const __attribute__((address_space(1))) unsigned int*)&A[(size_t)(m0 + row_p) * K + k0 + colE],
          (__attribute__((address_space(3))) unsigned int*)&As[(w * 4 + i) * 512],
          16, 0, 0);
      __builtin_amdgcn_global_load_lds(
          (const __attribute__((address_space(1))) unsigned int*)&Bt[(size_t)(n0 + row_p) * K + k0 + colE],
          (__attribute__((address_space(3))) unsigned int*)&Bs[(w * 4 + i) * 512],
          16, 0, 0);
    }
    __syncthreads();
#pragma unroll
    for (int kk = 0; kk < 2; ++kk) {
      bf16x8 a[4], bfr[4];
#pragma unroll
      for (int mi = 0; mi < 4; ++mi) {
        int row = wr * 64 + mi * 16 + ln16;
        int blk = (kk * 4 + l16) ^ (row & 7);
        a[mi] = *reinterpret_cast<const bf16x8*>(&As[row * 64 + blk * 8]);
      }
#pragma unroll
      for (int ni = 0; ni < 4; ++ni) {
        int row = wc * 64 + ni * 16 + ln16;
        int blk = (kk * 4 + l16) ^ (row & 7);
        bfr[ni] = *reinterpret_cast<const bf16x8*>(&Bs[row * 64 + blk * 8]);
      }
#pragma unroll
      for (int mi = 0; mi < 4; ++mi)
#pragma unroll
        for (int ni = 0; ni < 4; ++ni)
          acc[mi][ni] = __builtin_amdgcn_mfma_f32_16x16x32_bf16(a[mi], bfr[ni], acc[mi][ni], 0, 0, 0);
    }
    __syncthreads();
  }

#pragma unroll
  for (int mi = 0; mi < 4; ++mi)
#pragma unroll
    for (int ni = 0; ni < 4; ++ni)
#pragma unroll
      for (int ri = 0; ri < 4; ++ri) {
        int row = m0 + wr * 64 + mi * 16 + l16 * 4 + ri;
        int col = n0 + wc * 64 + ni * 16 + ln16;
        float v = acc[mi][ni][ri] + bias[col];
        if (OUTF32) {
          reinterpret_cast<float*>(Cout)[(size_t)row * N + col] = v;
        } else {
          if (n0 < DD) v *= QSCALE;  // Q block (uniform per block)
          short bv = f2bf(v);
          if (n0 >= 2 * DD) {
            // V block: write transposed to vt
            int bb = row >> 11, s = row & 2047;
            vtout[(size_t)(bb * 1024 + col - 2 * DD) * SS + s] = bv;
          } else {
            reinterpret_cast<short*>(Cout)[(size_t)row * N + col] = bv;
          }
        }
      }
}

// ---------------- Flash attention (R5 structure, exp2-domain softmax) ----------------
// grid (16, B*H), 512 threads. Waves 0-3 (g=0): even kt; waves 4-7 (g=1): odd kt.
// Wave wq owns q-rows [wq*16, wq*16+16). Block does q-tiles 31-pj then pj (uniform work).
// Scores arrive pre-scaled by QSCALE (log2 domain) -> exp2f everywhere. LDS 53248 B.
#define MASKV -3.0e38f
__global__ __launch_bounds__(512) void flash_attn_k(const short* __restrict__ qkv,
                                                    const short* __restrict__ vt,
                                                    short* __restrict__ ctx) {
  __shared__ __align__(16) char smem[53248];
  // [0,18432): Ks[2][64][72] ; [18432,36864): Vs[2][64][72] ; [36864,53248): Ps 8*16*64 shorts
  // (XOR-swizzled 16B blocks). Combine aliases: Od f32 dump at [0,16640), mls at [17408,17920).
  short (*Ks)[64][72] = reinterpret_cast<short(*)[64][72]>(smem);
  short (*Vs)[64][72] = reinterpret_cast<short(*)[64][72]>(smem + 18432);
  short* Psr = reinterpret_cast<short*>(smem + 36864);
  float* Od = reinterpret_cast<float*>(smem);
  float* mls = reinterpret_cast<float*>(smem + 17408);

  int tid = threadIdx.x;
  int pj = blockIdx.x;
  int bh = blockIdx.y;
  int b = bh >> 4, h = bh & 15;
  int wg = tid >> 6, lane = tid & 63;
  int g = wg >> 2, wq = wg & 3;
  int ln16 = lane & 15, l16 = lane >> 4;
  int t8 = tid & 255;
  int tb = tid >> 8;  // staging parity buffer this thread fills
  int r0 = t8 >> 3, cc0 = (t8 & 7) << 3;
  int psq = (wg << 10) + (ln16 << 6);  // Ps base (shorts) for this wave+q

  const short* kbase = qkv + (size_t)(b * SS) * N3D + DD + h * DHH;  // + s*N3D + d
  const short* vbase = vt + (size_t)(bh * DHH) * SS;                 // + d*SS + s

#pragma unroll 1
  for (int ti = 0; ti < 2; ++ti) {
    int qt = ti ? pj : 31 - pj;
    int q0 = qt * 64;

    bf16x8 qf[2];
    {
      const short* qrow = qkv + (size_t)(b * SS + q0 + wq * 16 + ln16) * N3D + h * DHH;
      qf[0] = *reinterpret_cast<const bf16x8*>(qrow + l16 * 8);
      qf[1] = *reinterpret_cast<const bf16x8*>(qrow + 32 + l16 * 8);
    }
    float m_ = -1e30f, l_ = 0.f;
    f32x4 cacc[4] = {};

    int ns = (qt + 2) >> 1;
    uint4 kr0, kr1, vr0, vr1;
    {
      int kt_s = tb <= qt ? tb : qt;
      kr0 = *reinterpret_cast<const uint4*>(kbase + (size_t)(kt_s * 64 + r0) * N3D + cc0);
      kr1 = *reinterpret_cast<const uint4*>(kbase + (size_t)(kt_s * 64 + r0 + 32) * N3D + cc0);
      vr0 = *reinterpret_cast<const uint4*>(vbase + (size_t)r0 * SS + kt_s * 64 + cc0);
      vr1 = *reinterpret_cast<const uint4*>(vbase + (size_t)(r0 + 32) * SS + kt_s * 64 + cc0);
    }

#pragma unroll 1
    for (int s = 0; s < ns; ++s) {
      *reinterpret_cast<uint4*>(&Ks[tb][r0][cc0]) = kr0;
      *reinterpret_cast<uint4*>(&Ks[tb][r0 + 32][cc0]) = kr1;
      *reinterpret_cast<uint4*>(&Vs[tb][r0][cc0]) = vr0;
      *reinterpret_cast<uint4*>(&Vs[tb][r0 + 32][cc0]) = vr1;
      __syncthreads();

      // prefetch next super-iter (clamped; latency hides under softmax+PV)
      {
        int kt_n = 2 * (s + 1) + tb;
        if (kt_n > qt) kt_n = qt;
        kr0 = *reinterpret_cast<const uint4*>(kbase + (size_t)(kt_n * 64 + r0) * N3D + cc0);
        kr1 = *reinterpret_cast<const uint4*>(kbase + (size_t)(kt_n * 64 + r0 + 32) * N3D + cc0);
        vr0 = *reinterpret_cast<const uint4*>(vbase + (size_t)r0 * SS + kt_n * 64 + cc0);
        vr1 = *reinterpret_cast<const uint4*>(vbase + (size_t)(r0 + 32) * SS + kt_n * 64 + cc0);
      }

      int kt_c = 2 * s + g;
      if (kt_c <= qt) {
        // QK^T swapped: sacc[ni][ri] = S^T[k = ni*16+l16*4+ri][q = ln16]  (log2-scaled)
        f32x4 sacc[4] = {};
#pragma unroll
        for (int kk = 0; kk < 2; ++kk)
#pragma unroll
          for (int ni = 0; ni < 4; ++ni) {
            bf16x8 kf = *reinterpret_cast<const bf16x8*>(&Ks[g][ni * 16 + ln16][kk * 32 + l16 * 8]);
            sacc[ni] = __builtin_amdgcn_mfma_f32_16x16x32_bf16(kf, qf[kk], sacc[ni], 0, 0, 0);
          }

        float p[4][4];
        float mx = MASKV;
        if (kt_c == qt) {  // diagonal tile: causal mask
          int qg = q0 + wq * 16 + ln16;
#pragma unroll
          for (int ni = 0; ni < 4; ++ni)
#pragma unroll
            for (int ri = 0; ri < 4; ++ri) {
              int kg = kt_c * 64 + ni * 16 + l16 * 4 + ri;
              float v = (kg > qg) ? MASKV : sacc[ni][ri];
              p[ni][ri] = v;
              mx = fmaxf(mx, v);
            }
        } else {
#pragma unroll
          for (int ni = 0; ni < 4; ++ni)
#pragma unroll
            for (int ri = 0; ri < 4; ++ri) {
              p[ni][ri] = sacc[ni][ri];
              mx = fmaxf(mx, sacc[ni][ri]);
            }
        }
        mx = fmaxf(mx, __shfl_xor(mx, 16));
        mx = fmaxf(mx, __shfl_xor(mx, 32));

        // defer-max (T13), log2 domain: rescale only when max grew by > 11.5
        int keep = __all(mx <= m_ + 11.5f);
        float mn = m_;
        if (!keep) {
          mn = fmaxf(m_, mx);
          float sc = exp2f(m_ - mn);
          l_ *= sc;
          float scr[4];
#pragma unroll
          for (int ri = 0; ri < 4; ++ri) scr[ri] = __shfl(sc, l16 * 4 + ri);
#pragma unroll
          for (int di = 0; di < 4; ++di)
#pragma unroll
            for (int ri = 0; ri < 4; ++ri) cacc[di][ri] *= scr[ri];
          m_ = mn;
        }

        float sum = 0.f;
#pragma unroll
        for (int ni = 0; ni < 4; ++ni)
#pragma unroll
          for (int ri = 0; ri < 4; ++ri) {
            float e = exp2f(p[ni][ri] - mn);
            p[ni][ri] = e;
            sum += e;
          }
        sum += __shfl_xor(sum, 16);
        sum += __shfl_xor(sum, 32);
        l_ += sum;

        // pack P -> Ps[wave][q=ln16][k], XOR-swizzled 16B blocks (blk ^= q&7)
#pragma unroll
        for (int ni = 0; ni < 4; ++ni) {
          uint2 u;
          u.x = cvtpk_bf16(p[ni][0], p[ni][1]);
          u.y = cvtpk_bf16(p[ni][2], p[ni][3]);
          int idx = psq + ((((ni << 1) + (l16 >> 1)) ^ (ln16 & 7)) << 3) + ((l16 & 1) << 2);
          *reinterpret_cast<uint2*>(&Psr[idx]) = u;
        }
        asm volatile("s_waitcnt lgkmcnt(0)" ::: "memory");

        // ctx += P @ V
#pragma unroll
        for (int kk = 0; kk < 2; ++kk) {
          bf16x8 pa = *reinterpret_cast<const bf16x8*>(
              &Psr[psq + ((((kk << 2) + l16) ^ (ln16 & 7)) << 3)]);
#pragma unroll
          for (int di = 0; di < 4; ++di) {
            bf16x8 vb = *reinterpret_cast<const bf16x8*>(&Vs[g][di * 16 + ln16][kk * 32 + l16 * 8]);
            cacc[di] = __builtin_amdgcn_mfma_f32_16x16x32_bf16(pa, vb, cacc[di], 0, 0, 0);
          }
        }
      }
      __syncthreads();
    }

    // ---- combine even/odd partials (aliases Ks/Vs region; all kv reads done) ----
    if (g == 1) {
      if (l16 == 0) { mls[wq * 16 + ln16] = m_; mls[64 + wq * 16 + ln16] = l_; }
#pragma unroll
      for (int di = 0; di < 4; ++di)
#pragma unroll
        for (int ri = 0; ri < 4; ++ri)
          Od[wq * 1040 + (l16 * 4 + ri) * 65 + di * 16 + ln16] = cacc[di][ri];
    }
    __syncthreads();
    if (g == 0) {
      float m1 = mls[wq * 16 + ln16], l1 = mls[64 + wq * 16 + ln16];
      float mM = fmaxf(m_, m1);
      float e0 = exp2f(m_ - mM), e1 = exp2f(m1 - mM);
      float inv = 1.f / (l_ * e0 + l1 * e1);
      float e0r[4], e1r[4], ivr[4];
#pragma unroll
      for (int ri = 0; ri < 4; ++ri) {
        int src = l16 * 4 + ri;
        e0r[ri] = __shfl(e0, src);
        e1r[ri] = __shfl(e1, src);
        ivr[ri] = __shfl(inv, src);
      }
#pragma unroll
      for (int di = 0; di < 4; ++di)
#pragma unroll
        for (int ri = 0; ri < 4; ++ri) {
          float a1 = Od[wq * 1040 + (l16 * 4 + ri) * 65 + di * 16 + ln16];
          float o = (cacc[di][ri] * e0r[ri] + a1 * e1r[ri]) * ivr[ri];
          int row = q0 + wq * 16 + l16 * 4 + ri;
          int col = h * DHH + di * 16 + ln16;
          ctx[(size_t)(b * SS + row) * DD + col] = f2bf(o);
        }
    }
    __syncthreads();
  }
}

extern "C" void kernel_launch(void* const* d_in, const int* in_sizes, int n_in,
                              void* d_out, int out_size, void* d_ws, size_t ws_size,
                              hipStream_t stream) {
  const float* x      = (const float*)d_in[0];
  const float* w_attn = (const float*)d_in[1];
  const float* b_attn = (const float*)d_in[2];
  const float* w_proj = (const float*)d_in[3];
  const float* b_proj = (const float*)d_in[4];
  float* out = (float*)d_out;

  char* ws = (char*)d_ws;
  short* xb     = (short*)(ws);                       // 8388608 B
  short* wattnT = (short*)(ws + 8388608);             // 6291456 B
  short* wprojT = (short*)(ws + 14680064);            // 2097152 B
  short* qkv    = (short*)(ws + 16777216);            // 25165824 B (V third unused)
  short* vt     = (short*)(ws + 41943040);            // 8388608 B
  short* ctx    = (short*)(ws + 50331648);            // 8388608 B

  {
    int n4 = (MTOK * DD) / 4;
    cast_bf16_k<<<(n4 + 255) / 256, 256, 0, stream>>>(x, xb, n4);
  }
  transpose_cast_k<<<dim3(N3D / 32, DD / 32), dim3(32, 8), 0, stream>>>(w_attn, wattnT, DD, N3D);
  transpose_cast_k<<<dim3(DD / 32, DD / 32), dim3(32, 8), 0, stream>>>(w_proj, wprojT, DD, DD);
  // QKV GEMM: writes Q (scaled) + K to qkv, V transposed to vt
  gemm128_k<0><<<dim3(N3D / 128, MTOK / 128), 256, 0, stream>>>(xb, wattnT, b_attn, qkv, vt, MTOK, N3D, DD);
  flash_attn_k<<<dim3(16, BB * HH), 512, 0, stream>>>(qkv, vt, ctx);
  gemm128_k<1><<<dim3(DD / 128, MTOK / 128), 256, 0, stream>>>(ctx, wprojT, b_proj, out, nullptr, MTOK, DD, DD);
}

// Round 12
// 124.691 us; speedup vs baseline: 1.0675x; 1.0296x over previous
//
#include <hip/hip_runtime.h>
#include <hip/hip_bf16.h>

// GPT2 attention. B=2, S=2048, D=1024, H=16, DH=64.
// inputs (f32): x[2,2048,1024], w_attn[1024,3072], b_attn[3072], w_proj[1024,1024], b_proj[1024]
// output (f32): [2,2048,1024]

#define BB 2
#define SS 2048
#define DD 1024
#define HH 16
#define DHH 64
#define MTOK (BB * SS)        // 4096
#define N3D (3 * DD)          // 3072
// 1/sqrt(64) * log2(e): softmax runs in exp2 domain
#define QSCALE 0.18033688f

typedef __attribute__((ext_vector_type(8))) short bf16x8;
typedef __attribute__((ext_vector_type(4))) float f32x4;
typedef __attribute__((ext_vector_type(4))) short short4v;

__device__ __forceinline__ short f2bf(float f) {
  unsigned int x = __float_as_uint(f);
  unsigned int r = (x + 0x7fffu + ((x >> 16) & 1u)) >> 16;
  return (short)r;
}

__device__ __forceinline__ unsigned int cvtpk_bf16(float lo, float hi) {
  unsigned int r;
  asm("v_cvt_pk_bf16_f32 %0, %1, %2" : "=v"(r) : "v"(lo), "v"(hi));
  return r;
}

// native 2^x (v_exp_f32 IS exp2); plain exp2f() lowers to an ocml libcall with
// fixup code -- measured +11pp VALUBusy in round 11.
__device__ __forceinline__ float exp2n(float x) {
  float r;
  asm("v_exp_f32 %0, %1" : "=v"(r) : "v"(x));
  return r;
}

// ---------------- cast f32 -> bf16 (vectorized x4) ----------------
__global__ void cast_bf16_k(const float* __restrict__ in, short* __restrict__ out, int n4) {
  int i = blockIdx.x * blockDim.x + threadIdx.x;
  if (i < n4) {
    float4 v = reinterpret_cast<const float4*>(in)[i];
    short4v o;
    o[0] = f2bf(v.x); o[1] = f2bf(v.y); o[2] = f2bf(v.z); o[3] = f2bf(v.w);
    reinterpret_cast<short4v*>(out)[i] = o;
  }
}

// ---------------- transpose + cast: W[K][N] f32 -> Wt[N][K] bf16 ----------------
__global__ void transpose_cast_k(const float* __restrict__ W, short* __restrict__ Wt, int K, int N) {
  __shared__ float t[32][33];
  int n0 = blockIdx.x * 32, k0 = blockIdx.y * 32;
  int tx = threadIdx.x, ty = threadIdx.y;
#pragma unroll
  for (int i = 0; i < 4; ++i)
    t[ty + 8 * i][tx] = W[(size_t)(k0 + ty + 8 * i) * N + n0 + tx];
  __syncthreads();
#pragma unroll
  for (int i = 0; i < 4; ++i)
    Wt[(size_t)(n0 + ty + 8 * i) * K + k0 + tx] = f2bf(t[tx][ty + 8 * i]);
}

// ---------------- GEMM m97-structure: C[M][N] = A[M][K] * Bt[N][K]^T + bias ----------------
// OUTF32=0 (QKV): bf16 out; Q cols (n0<DD) pre-scaled by QSCALE; V cols (n0>=2DD) are
// written TRANSPOSED to vtout (vt[(b*1024 + col-2048)][s]) instead of qkv.
// OUTF32=1 (proj): f32 out, direct dword stores.
template <int OUTF32>
__global__ __launch_bounds__(256) void gemm128_k(const short* __restrict__ A,
                                                 const short* __restrict__ Bt,
                                                 const float* __restrict__ bias,
                                                 void* __restrict__ Cout,
                                                 short* __restrict__ vtout,
                                                 int M, int N, int K) {
  __shared__ short As[128 * 64];
  __shared__ short Bs[128 * 64];
  int tid = threadIdx.x;
  int m0 = blockIdx.y * 128, n0 = blockIdx.x * 128;
  int w = tid >> 6, lane = tid & 63;
  int wr = w >> 1, wc = w & 1;
  int ln16 = lane & 15, l16 = lane >> 4;

  f32x4 acc[4][4] = {};

  int lrow0 = w * 32 + (lane >> 3);
  int blk_p = lane & 7;

  for (int k0 = 0; k0 < K; k0 += 64) {
#pragma unroll
    for (int i = 0; i < 4; ++i) {
      int row_p = lrow0 + i * 8;
      int colE = ((blk_p ^ (row_p & 7)) << 3);
      __builtin_amdgcn_global_load_lds(
          (const __attribute__((address_space(1))) unsigned int*)&A[(size_t)(m0 + row_p) * K + k0 + colE],
          (__attribute__((address_space(3))) unsigned int*)&As[(w * 4 + i) * 512],
          16, 0, 0);
      __builtin_amdgcn_global_load_lds(
          (const __attribute__((address_space(1))) unsigned int*)&Bt[(size_t)(n0 + row_p) * K + k0 + colE],
          (__attribute__((address_space(3))) unsigned int*)&Bs[(w * 4 + i) * 512],
          16, 0, 0);
    }
    __syncthreads();
#pragma unroll
    for (int kk = 0; kk < 2; ++kk) {
      bf16x8 a[4], bfr[4];
#pragma unroll
      for (int mi = 0; mi < 4; ++mi) {
        int row = wr * 64 + mi * 16 + ln16;
        int blk = (kk * 4 + l16) ^ (row & 7);
        a[mi] = *reinterpret_cast<const bf16x8*>(&As[row * 64 + blk * 8]);
      }
#pragma unroll
      for (int ni = 0; ni < 4; ++ni) {
        int row = wc * 64 + ni * 16 + ln16;
        int blk = (kk * 4 + l16) ^ (row & 7);
        bfr[ni] = *reinterpret_cast<const bf16x8*>(&Bs[row * 64 + blk * 8]);
      }
#pragma unroll
      for (int mi = 0; mi < 4; ++mi)
#pragma unroll
        for (int ni = 0; ni < 4; ++ni)
          acc[mi][ni] = __builtin_amdgcn_mfma_f32_16x16x32_bf16(a[mi], bfr[ni], acc[mi][ni], 0, 0, 0);
    }
    __syncthreads();
  }

#pragma unroll
  for (int mi = 0; mi < 4; ++mi)
#pragma unroll
    for (int ni = 0; ni < 4; ++ni)
#pragma unroll
      for (int ri = 0; ri < 4; ++ri) {
        int row = m0 + wr * 64 + mi * 16 + l16 * 4 + ri;
        int col = n0 + wc * 64 + ni * 16 + ln16;
        float v = acc[mi][ni][ri] + bias[col];
        if (OUTF32) {
          reinterpret_cast<float*>(Cout)[(size_t)row * N + col] = v;
        } else {
          if (n0 < DD) v *= QSCALE;  // Q block (uniform per block)
          short bv = f2bf(v);
          if (n0 >= 2 * DD) {
            // V block: write transposed to vt
            int bb = row >> 11, s = row & 2047;
            vtout[(size_t)(bb * 1024 + col - 2 * DD) * SS + s] = bv;
          } else {
            reinterpret_cast<short*>(Cout)[(size_t)row * N + col] = bv;
          }
        }
      }
}

// ---------------- Flash attention (R5 structure, exp2-domain softmax, native v_exp) ----------------
// grid (16, B*H), 512 threads. Waves 0-3 (g=0): even kt; waves 4-7 (g=1): odd kt.
// Wave wq owns q-rows [wq*16, wq*16+16). Block does q-tiles 31-pj then pj (uniform work).
// Scores arrive pre-scaled by QSCALE (log2 domain). LDS 53248 B.
#define MASKV -3.0e38f
__global__ __launch_bounds__(512) void flash_attn_k(const short* __restrict__ qkv,
                                                    const short* __restrict__ vt,
                                                    short* __restrict__ ctx) {
  __shared__ __align__(16) char smem[53248];
  // [0,18432): Ks[2][64][72] ; [18432,36864): Vs[2][64][72] ; [36864,53248): Ps 8*16*64 shorts
  // (XOR-swizzled 16B blocks). Combine aliases: Od f32 dump at [0,16640), mls at [17408,17920).
  short (*Ks)[64][72] = reinterpret_cast<short(*)[64][72]>(smem);
  short (*Vs)[64][72] = reinterpret_cast<short(*)[64][72]>(smem + 18432);
  short* Psr = reinterpret_cast<short*>(smem + 36864);
  float* Od = reinterpret_cast<float*>(smem);
  float* mls = reinterpret_cast<float*>(smem + 17408);

  int tid = threadIdx.x;
  int pj = blockIdx.x;
  int bh = blockIdx.y;
  int b = bh >> 4, h = bh & 15;
  int wg = tid >> 6, lane = tid & 63;
  int g = wg >> 2, wq = wg & 3;
  int ln16 = lane & 15, l16 = lane >> 4;
  int t8 = tid & 255;
  int tb = tid >> 8;  // staging parity buffer this thread fills
  int r0 = t8 >> 3, cc0 = (t8 & 7) << 3;
  int psq = (wg << 10) + (ln16 << 6);  // Ps base (shorts) for this wave+q

  const short* kbase = qkv + (size_t)(b * SS) * N3D + DD + h * DHH;  // + s*N3D + d
  const short* vbase = vt + (size_t)(bh * DHH) * SS;                 // + d*SS + s

#pragma unroll 1
  for (int ti = 0; ti < 2; ++ti) {
    int qt = ti ? pj : 31 - pj;
    int q0 = qt * 64;

    bf16x8 qf[2];
    {
      const short* qrow = qkv + (size_t)(b * SS + q0 + wq * 16 + ln16) * N3D + h * DHH;
      qf[0] = *reinterpret_cast<const bf16x8*>(qrow + l16 * 8);
      qf[1] = *reinterpret_cast<const bf16x8*>(qrow + 32 + l16 * 8);
    }
    float m_ = -1e30f, l_ = 0.f;
    f32x4 cacc[4] = {};

    int ns = (qt + 2) >> 1;
    uint4 kr0, kr1, vr0, vr1;
    {
      int kt_s = tb <= qt ? tb : qt;
      kr0 = *reinterpret_cast<const uint4*>(kbase + (size_t)(kt_s * 64 + r0) * N3D + cc0);
      kr1 = *reinterpret_cast<const uint4*>(kbase + (size_t)(kt_s * 64 + r0 + 32) * N3D + cc0);
      vr0 = *reinterpret_cast<const uint4*>(vbase + (size_t)r0 * SS + kt_s * 64 + cc0);
      vr1 = *reinterpret_cast<const uint4*>(vbase + (size_t)(r0 + 32) * SS + kt_s * 64 + cc0);
    }

#pragma unroll 1
    for (int s = 0; s < ns; ++s) {
      *reinterpret_cast<uint4*>(&Ks[tb][r0][cc0]) = kr0;
      *reinterpret_cast<uint4*>(&Ks[tb][r0 + 32][cc0]) = kr1;
      *reinterpret_cast<uint4*>(&Vs[tb][r0][cc0]) = vr0;
      *reinterpret_cast<uint4*>(&Vs[tb][r0 + 32][cc0]) = vr1;
      __syncthreads();

      // prefetch next super-iter (clamped; latency hides under softmax+PV)
      {
        int kt_n = 2 * (s + 1) + tb;
        if (kt_n > qt) kt_n = qt;
        kr0 = *reinterpret_cast<const uint4*>(kbase + (size_t)(kt_n * 64 + r0) * N3D + cc0);
        kr1 = *reinterpret_cast<const uint4*>(kbase + (size_t)(kt_n * 64 + r0 + 32) * N3D + cc0);
        vr0 = *reinterpret_cast<const uint4*>(vbase + (size_t)r0 * SS + kt_n * 64 + cc0);
        vr1 = *reinterpret_cast<const uint4*>(vbase + (size_t)(r0 + 32) * SS + kt_n * 64 + cc0);
      }

      int kt_c = 2 * s + g;
      if (kt_c <= qt) {
        // QK^T swapped: sacc[ni][ri] = S^T[k = ni*16+l16*4+ri][q = ln16]  (log2-scaled)
        f32x4 sacc[4] = {};
#pragma unroll
        for (int kk = 0; kk < 2; ++kk)
#pragma unroll
          for (int ni = 0; ni < 4; ++ni) {
            bf16x8 kf = *reinterpret_cast<const bf16x8*>(&Ks[g][ni * 16 + ln16][kk * 32 + l16 * 8]);
            sacc[ni] = __builtin_amdgcn_mfma_f32_16x16x32_bf16(kf, qf[kk], sacc[ni], 0, 0, 0);
          }

        float p[4][4];
        float mx = MASKV;
        if (kt_c == qt) {  // diagonal tile: causal mask
          int qg = q0 + wq * 16 + ln16;
#pragma unroll
          for (int ni = 0; ni < 4; ++ni)
#pragma unroll
            for (int ri = 0; ri < 4; ++ri) {
              int kg = kt_c * 64 + ni * 16 + l16 * 4 + ri;
              float v = (kg > qg) ? MASKV : sacc[ni][ri];
              p[ni][ri] = v;
              mx = fmaxf(mx, v);
            }
        } else {
#pragma unroll
          for (int ni = 0; ni < 4; ++ni)
#pragma unroll
            for (int ri = 0; ri < 4; ++ri) {
              p[ni][ri] = sacc[ni][ri];
              mx = fmaxf(mx, sacc[ni][ri]);
            }
        }
        mx = fmaxf(mx, __shfl_xor(mx, 16));
        mx = fmaxf(mx, __shfl_xor(mx, 32));

        // defer-max (T13), log2 domain: rescale only when max grew by > 11.5
        int keep = __all(mx <= m_ + 11.5f);
        float mn = m_;
        if (!keep) {
          mn = fmaxf(m_, mx);
          float sc = exp2n(m_ - mn);
          l_ *= sc;
          float scr[4];
#pragma unroll
          for (int ri = 0; ri < 4; ++ri) scr[ri] = __shfl(sc, l16 * 4 + ri);
#pragma unroll
          for (int di = 0; di < 4; ++di)
#pragma unroll
            for (int ri = 0; ri < 4; ++ri) cacc[di][ri] *= scr[ri];
          m_ = mn;
        }

        float sum = 0.f;
#pragma unroll
        for (int ni = 0; ni < 4; ++ni)
#pragma unroll
          for (int ri = 0; ri < 4; ++ri) {
            float e = exp2n(p[ni][ri] - mn);
            p[ni][ri] = e;
            sum += e;
          }
        sum += __shfl_xor(sum, 16);
        sum += __shfl_xor(sum, 32);
        l_ += sum;

        // pack P -> Ps[wave][q=ln16][k], XOR-swizzled 16B blocks (blk ^= q&7)
#pragma unroll
        for (int ni = 0; ni < 4; ++ni) {
          uint2 u;
          u.x = cvtpk_bf16(p[ni][0], p[ni][1]);
          u.y = cvtpk_bf16(p[ni][2], p[ni][3]);
          int idx = psq + ((((ni << 1) + (l16 >> 1)) ^ (ln16 & 7)) << 3) + ((l16 & 1) << 2);
          *reinterpret_cast<uint2*>(&Psr[idx]) = u;
        }
        asm volatile("s_waitcnt lgkmcnt(0)" ::: "memory");

        // ctx += P @ V
#pragma unroll
        for (int kk = 0; kk < 2; ++kk) {
          bf16x8 pa = *reinterpret_cast<const bf16x8*>(
              &Psr[psq + ((((kk << 2) + l16) ^ (ln16 & 7)) << 3)]);
#pragma unroll
          for (int di = 0; di < 4; ++di) {
            bf16x8 vb = *reinterpret_cast<const bf16x8*>(&Vs[g][di * 16 + ln16][kk * 32 + l16 * 8]);
            cacc[di] = __builtin_amdgcn_mfma_f32_16x16x32_bf16(pa, vb, cacc[di], 0, 0, 0);
          }
        }
      }
      __syncthreads();
    }

    // ---- combine even/odd partials (aliases Ks/Vs region; all kv reads done) ----
    if (g == 1) {
      if (l16 == 0) { mls[wq * 16 + ln16] = m_; mls[64 + wq * 16 + ln16] = l_; }
#pragma unroll
      for (int di = 0; di < 4; ++di)
#pragma unroll
        for (int ri = 0; ri < 4; ++ri)
          Od[wq * 1040 + (l16 * 4 + ri) * 65 + di * 16 + ln16] = cacc[di][ri];
    }
    __syncthreads();
    if (g == 0) {
      float m1 = mls[wq * 16 + ln16], l1 = mls[64 + wq * 16 + ln16];
      float mM = fmaxf(m_, m1);
      float e0 = exp2n(m_ - mM), e1 = exp2n(m1 - mM);
      float inv = 1.f / (l_ * e0 + l1 * e1);
      float e0r[4], e1r[4], ivr[4];
#pragma unroll
      for (int ri = 0; ri < 4; ++ri) {
        int src = l16 * 4 + ri;
        e0r[ri] = __shfl(e0, src);
        e1r[ri] = __shfl(e1, src);
        ivr[ri] = __shfl(inv, src);
      }
#pragma unroll
      for (int di = 0; di < 4; ++di)
#pragma unroll
        for (int ri = 0; ri < 4; ++ri) {
          float a1 = Od[wq * 1040 + (l16 * 4 + ri) * 65 + di * 16 + ln16];
          float o = (cacc[di][ri] * e0r[ri] + a1 * e1r[ri]) * ivr[ri];
          int row = q0 + wq * 16 + l16 * 4 + ri;
          int col = h * DHH + di * 16 + ln16;
          ctx[(size_t)(b * SS + row) * DD + col] = f2bf(o);
        }
    }
    __syncthreads();
  }
}

extern "C" void kernel_launch(void* const* d_in, const int* in_sizes, int n_in,
                              void* d_out, int out_size, void* d_ws, size_t ws_size,
                              hipStream_t stream) {
  const float* x      = (const float*)d_in[0];
  const float* w_attn = (const float*)d_in[1];
  const float* b_attn = (const float*)d_in[2];
  const float* w_proj = (const float*)d_in[3];
  const float* b_proj = (const float*)d_in[4];
  float* out = (float*)d_out;

  char* ws = (char*)d_ws;
  short* xb     = (short*)(ws);                       // 8388608 B
  short* wattnT = (short*)(ws + 8388608);             // 6291456 B
  short* wprojT = (short*)(ws + 14680064);            // 2097152 B
  short* qkv    = (short*)(ws + 16777216);            // 25165824 B (V third unused)
  short* vt     = (short*)(ws + 41943040);            // 8388608 B
  short* ctx    = (short*)(ws + 50331648);            // 8388608 B

  {
    int n4 = (MTOK * DD) / 4;
    cast_bf16_k<<<(n4 + 255) / 256, 256, 0, stream>>>(x, xb, n4);
  }
  transpose_cast_k<<<dim3(N3D / 32, DD / 32), dim3(32, 8), 0, stream>>>(w_attn, wattnT, DD, N3D);
  transpose_cast_k<<<dim3(DD / 32, DD / 32), dim3(32, 8), 0, stream>>>(w_proj, wprojT, DD, DD);
  // QKV GEMM: writes Q (scaled) + K to qkv, V transposed to vt
  gemm128_k<0><<<dim3(N3D / 128, MTOK / 128), 256, 0, stream>>>(xb, wattnT, b_attn, qkv, vt, MTOK, N3D, DD);
  flash_attn_k<<<dim3(16, BB * HH), 512, 0, stream>>>(qkv, vt, ctx);
  gemm128_k<1><<<dim3(DD / 128, MTOK / 128), 256, 0, stream>>>(ctx, wprojT, b_proj, out, nullptr, MTOK, DD, DD);
}